// Round 8
// baseline (151.795 us; speedup 1.0000x reference)
//
#include <hip/hip_runtime.h>
#include <hip/hip_bf16.h>
#include <cstdint>
#include <cstddef>

#define NQH 16
#define NKH 4
#define HN 128
#define QBLK 64
#define KBLK 64
#define QSCALE 0.12751589542585458f  // (1/sqrt(128)) * log2(e)
#define TILEB 16384                  // KBLK*HN*2 bytes per K or V tile

// ---- workspace layout (bytes) ----
#define STAGE_B (8u << 20)                  // Kb(4MB) + Vb(4MB)
#define TAB_OFF STAGE_B                     // int4 hdr + int4 units[128] + slot_r0[64]
#define TAB_B 4096u
#define ML_OFF (TAB_OFF + TAB_B)
#define ML_FLOATS_HALF (64 * 16 * 64 * 2)   // per array: [slot][head][row][2]
#define ML_B (2u * ML_FLOATS_HALF * 4u)     // ml0 + ml1 = 1 MB
#define ACC_OFF (ML_OFF + ML_B)
#define SLOT_FLOATS (16 * 64 * 128)         // per split slot: [head][row][128]
#define SPLIT_MIN 13

typedef __bf16 bf16x8 __attribute__((ext_vector_type(8)));
typedef float f32x4 __attribute__((ext_vector_type(4)));

__device__ __forceinline__ void gload16(const void* g, void* l) {
  __builtin_amdgcn_global_load_lds(
      (const __attribute__((address_space(1))) void*)g,
      (__attribute__((address_space(3))) void*)l, 16, 0, 0);
}

// ---- setup: build work-unit table from cu_seqlens ----
// unit = {r0, key_begin, key_end, mode | slot<<2}; mode 0=full 1=chunk0 2=chunk1
__global__ void setup_units(const int* __restrict__ cu, int nseg, int T,
                            unsigned long long cap, char* __restrict__ ws) {
  if (threadIdx.x != 0) return;
  int4* tab = (int4*)(ws + TAB_OFF);
  int* slot_r0 = (int*)(ws + TAB_OFF + 129 * 16);
  const int nt = T / QBLK;  // 64
  int nkb[64], kst[64];
  int spl = 0;
  for (int t = 0; t < nt; ++t) {
    const int r0 = t * QBLK;
    int st0 = 0;
    for (int s = 1; s < nseg; ++s) {
      const int c = cu[s];
      if (c <= r0) st0 = c;
    }
    kst[t] = st0 & ~(KBLK - 1);
    nkb[t] = (r0 + QBLK - kst[t]) / KBLK;
    if (nkb[t] >= SPLIT_MIN) spl++;
  }
  const unsigned long long need =
      (unsigned long long)ACC_OFF + (unsigned long long)spl * SLOT_FLOATS * 4u;
  const int enabled = (need <= cap) ? 1 : 0;
  int nu = 0, slot = 0;
  for (int t = nt - 1; t >= 0; --t) {  // reverse = heavy-first (within segs)
    const int r0 = t * QBLK;
    if (enabled && nkb[t] >= SPLIT_MIN) {
      const int h0 = (nkb[t] + 1) >> 1;
      const int kmid = kst[t] + h0 * KBLK;
      tab[1 + nu] = make_int4(r0, kst[t], kmid, 1 | (slot << 2)); nu++;
      tab[1 + nu] = make_int4(r0, kmid, r0 + QBLK, 2 | (slot << 2)); nu++;
      slot_r0[slot] = r0; slot++;
    } else {
      tab[1 + nu] = make_int4(r0, kst[t], r0 + QBLK, 0); nu++;
    }
  }
  tab[0] = make_int4(nu, slot, enabled, 0);
}

// ---- pre-kernel A: K f32 [T][4][128] -> Kb bf16 [4][T][128] ----
__global__ __launch_bounds__(256) void cvt_k(const float* __restrict__ K,
                                             __bf16* __restrict__ Kb, int T) {
  const size_t idx8 = ((size_t)blockIdx.x * 256 + threadIdx.x) * 8;
  const int d = (int)(idx8 & 127);
  const int kvh = (int)((idx8 >> 7) & 3);
  const size_t t = idx8 >> 9;
  float4 a = *(const float4*)&K[idx8];
  float4 b = *(const float4*)&K[idx8 + 4];
  bf16x8 f;
  f[0] = (__bf16)a.x; f[1] = (__bf16)a.y; f[2] = (__bf16)a.z; f[3] = (__bf16)a.w;
  f[4] = (__bf16)b.x; f[5] = (__bf16)b.y; f[6] = (__bf16)b.z; f[7] = (__bf16)b.w;
  *(bf16x8*)&Kb[(size_t)kvh * T * HN + t * HN + d] = f;
}

// ---- pre-kernel B: V f32 [T][4][128] -> Vb bf16 [4][128][T] (transposed) ----
__global__ __launch_bounds__(128) void cvt_v(const float* __restrict__ V,
                                             __bf16* __restrict__ Vb, int T) {
  const int d = threadIdx.x;
  const int t0 = blockIdx.x * 8;
  const int kvh = blockIdx.y;
  bf16x8 f;
#pragma unroll
  for (int i = 0; i < 8; ++i)
    f[i] = (__bf16)V[(size_t)(t0 + i) * (NKH * HN) + kvh * HN + d];
  *(bf16x8*)&Vb[(size_t)kvh * HN * T + (size_t)d * T + t0] = f;
}

// ---- one KV-block iteration: swapped MFMA, in-register P (permuted K rows) ----
template <bool MASKED>
__device__ __forceinline__ void attn_iter(const char* Kc, const char* Vc,
                                          const bf16x8 qf[4], int ln, int hi,
                                          int lim, float& m_, float& l_,
                                          f32x4* acc) {
  f32x4 sT[4];
#pragma unroll
  for (int c = 0; c < 4; ++c) sT[c] = (f32x4){0.f, 0.f, 0.f, 0.f};
  __builtin_amdgcn_s_setprio(1);
#pragma unroll
  for (int kc = 0; kc < 4; ++kc) {
#pragma unroll
    for (int c = 0; c < 4; ++c) {
      const int row = c * 16 + ln;
      const bf16x8 kf =
          *(const bf16x8*)(Kc + row * 256 + (((kc * 4 + hi) ^ (row & 7)) << 4));
      sT[c] = __builtin_amdgcn_mfma_f32_16x16x32_bf16(kf, qf[kc], sT[c], 0, 0, 0);
    }
  }
  __builtin_amdgcn_s_setprio(0);

  if (MASKED) {
#pragma unroll
    for (int c = 0; c < 4; ++c)
#pragma unroll
      for (int i = 0; i < 4; ++i) {
        const int koff = ((c >> 1) << 5) + hi * 8 + ((c & 1) << 2) + i;
        sT[c][i] = (koff <= lim) ? sT[c][i] : -1e30f;
      }
  }

  float mm = fmaxf(
      fmaxf(fmaxf(fmaxf(sT[0][0], sT[0][1]), fmaxf(sT[0][2], sT[0][3])),
            fmaxf(fmaxf(sT[1][0], sT[1][1]), fmaxf(sT[1][2], sT[1][3]))),
      fmaxf(fmaxf(fmaxf(sT[2][0], sT[2][1]), fmaxf(sT[2][2], sT[2][3])),
            fmaxf(fmaxf(sT[3][0], sT[3][1]), fmaxf(sT[3][2], sT[3][3]))));
  mm = fmaxf(mm, __shfl_xor(mm, 16));
  mm = fmaxf(mm, __shfl_xor(mm, 32));

  if (__any(mm > m_ + 8.0f)) {  // defer-max THR=8 (exp2 domain)
    const float mnew = fmaxf(m_, mm);
    const float corr = exp2f(m_ - mnew);
    m_ = mnew;
    l_ *= corr;
#pragma unroll
    for (int dt = 0; dt < 8; ++dt) acc[dt] *= corr;
  }

  float p[4][4];
  float ps = 0.f;
#pragma unroll
  for (int c = 0; c < 4; ++c)
#pragma unroll
    for (int i = 0; i < 4; ++i) {
      p[c][i] = exp2f(sT[c][i] - m_);
      ps += p[c][i];
    }
  ps += __shfl_xor(ps, 16);
  ps += __shfl_xor(ps, 32);
  l_ += ps;

  bf16x8 pa[2];
#pragma unroll
  for (int ch = 0; ch < 2; ++ch)
#pragma unroll
    for (int e = 0; e < 8; ++e)
      pa[ch][e] = (__bf16)p[2 * ch + (e >> 2)][e & 3];

  __builtin_amdgcn_s_setprio(1);
#pragma unroll
  for (int ch = 0; ch < 2; ++ch) {
#pragma unroll
    for (int dt = 0; dt < 8; ++dt) {
      const int vr = dt * 16 + ln;
      const bf16x8 vb =
          *(const bf16x8*)(Vc + vr * 128 + (((ch * 4 + hi) ^ (vr & 7)) << 4));
      acc[dt] = __builtin_amdgcn_mfma_f32_16x16x32_bf16(vb, pa[ch], acc[dt], 0, 0, 0);
    }
  }
  __builtin_amdgcn_s_setprio(0);
}

// ---- main kernel: table-driven units; 8 waves, 2 q-heads share KV tiles ----
__global__ __launch_bounds__(512, 4) void attn_mfma6(
    const float* __restrict__ Q, const __bf16* __restrict__ Kb,
    const __bf16* __restrict__ Vb, char* __restrict__ ws,
    float* __restrict__ O, int T) {
  const int4* tab = (const int4*)(ws + TAB_OFF);
  const int nunits = tab[0].x;
  if ((int)blockIdx.x >= nunits) return;
  const int4 e = tab[1 + blockIdx.x];
  const int r0 = e.x, kbeg = e.y, kend = e.z;
  const int mode = e.w & 3, slot = e.w >> 2;
  const int nloc = (kend - kbeg) / KBLK;
  const bool diag = (kend == r0 + QBLK);

  const int tid = threadIdx.x;
  const int w = tid >> 6, lane = tid & 63;
  const int wg = w >> 2, wl = w & 3;
  const int ln = lane & 15, hi = lane >> 4;
  const int y = blockIdx.y;
  const int kvh = y >> 1;
  const int h = kvh * 4 + (y & 1) * 2 + wg;

  __shared__ __bf16 K_lds[2][KBLK * HN];
  __shared__ __bf16 V_lds[2][HN * KBLK];

  const __bf16* KbH = Kb + (size_t)kvh * T * HN;
  const __bf16* VbH = Vb + (size_t)kvh * HN * T;

  bf16x8 qf[4];
  {
    const float* qp = &Q[(size_t)(r0 + wl * 16 + ln) * (NQH * HN) + h * HN];
#pragma unroll
    for (int kc = 0; kc < 4; ++kc) {
      float4 a = *(const float4*)(qp + kc * 32 + hi * 8);
      float4 b = *(const float4*)(qp + kc * 32 + hi * 8 + 4);
      bf16x8 f;
      f[0] = (__bf16)(a.x * QSCALE); f[1] = (__bf16)(a.y * QSCALE);
      f[2] = (__bf16)(a.z * QSCALE); f[3] = (__bf16)(a.w * QSCALE);
      f[4] = (__bf16)(b.x * QSCALE); f[5] = (__bf16)(b.y * QSCALE);
      f[6] = (__bf16)(b.z * QSCALE); f[7] = (__bf16)(b.w * QSCALE);
      qf[kc] = f;
    }
  }

  float m_ = -1e30f, l_ = 0.f;
  f32x4 acc[8];
#pragma unroll
  for (int dt = 0; dt < 8; ++dt) acc[dt] = (f32x4){0.f, 0.f, 0.f, 0.f};

  // K staging: LDS row R holds key kb + sigma(R); sigma matches QK->PV koff map
  const int kR = w * 4 + hi;
  int keyoff[2];
#pragma unroll
  for (int j = 0; j < 2; ++j) {
    const int R = j * 32 + kR;
    const int c = R >> 4, r = R & 15;
    keyoff[j] = ((c >> 1) << 5) + ((r >> 2) << 3) + ((c & 1) << 2) + (r & 3);
  }
  const int kcol = ((ln ^ (kR & 7)) << 3);
  const int vrow = w * 8 + (lane >> 3);
  const int vcol = (((lane & 7) ^ ((lane >> 3) & 7)) << 3);
  char* ldsK0 = (char*)&K_lds[0][0] + w * 1024 + (size_t)lane * 16;
  char* ldsV0 = (char*)&V_lds[0][0] + w * 1024 + (size_t)lane * 16;

#pragma unroll
  for (int j = 0; j < 2; ++j)
    gload16(KbH + (size_t)(kbeg + keyoff[j]) * HN + kcol, ldsK0 + j * 8192);
#pragma unroll
  for (int j = 0; j < 2; ++j)
    gload16(VbH + (size_t)(j * 64 + vrow) * T + kbeg + vcol, ldsV0 + j * 8192);
  __syncthreads();

  for (int it = 0; it < nloc - 1; ++it) {
    const int cur = it & 1;
    const int kn = kbeg + (it + 1) * KBLK;
    char* dK = ldsK0 + (cur ^ 1) * TILEB;
    char* dV = ldsV0 + (cur ^ 1) * TILEB;
#pragma unroll
    for (int j = 0; j < 2; ++j)
      gload16(KbH + (size_t)(kn + keyoff[j]) * HN + kcol, dK + j * 8192);
#pragma unroll
    for (int j = 0; j < 2; ++j)
      gload16(VbH + (size_t)(j * 64 + vrow) * T + kn + vcol, dV + j * 8192);

    attn_iter<false>((const char*)&K_lds[0][0] + cur * TILEB,
                     (const char*)&V_lds[0][0] + cur * TILEB, qf, ln, hi, 0, m_,
                     l_, acc);
    __syncthreads();
  }
  {
    const int cur = (nloc - 1) & 1;
    const char* Kc = (const char*)&K_lds[0][0] + cur * TILEB;
    const char* Vc = (const char*)&V_lds[0][0] + cur * TILEB;
    if (diag)
      attn_iter<true>(Kc, Vc, qf, ln, hi, wl * 16 + ln, m_, l_, acc);
    else
      attn_iter<false>(Kc, Vc, qf, ln, hi, 0, m_, l_, acc);
  }

  const int rowl = wl * 16 + ln;
  if (mode == 0) {  // normal: normalized output
    const float inv = 1.0f / l_;
    float* op = &O[(size_t)(r0 + rowl) * (NQH * HN) + h * HN];
#pragma unroll
    for (int dt = 0; dt < 8; ++dt) {
      f32x4 res = acc[dt] * inv;
      *(f32x4*)&op[dt * 16 + hi * 4] = res;
    }
  } else {
    float* mlb = (float*)(ws + ML_OFF) + (mode == 2 ? ML_FLOATS_HALF : 0);
    if (hi == 0) {
      float* ml = mlb + (((size_t)slot * 16 + h) * 64 + rowl) * 2;
      ml[0] = m_; ml[1] = l_;
    }
    float* dst = (mode == 1)
                     ? &O[(size_t)(r0 + rowl) * (NQH * HN) + h * HN]
                     : (float*)(ws + ACC_OFF) + (size_t)slot * SLOT_FLOATS +
                           ((size_t)h * 64 + rowl) * HN;
#pragma unroll
    for (int dt = 0; dt < 8; ++dt) *(f32x4*)&dst[dt * 16 + hi * 4] = acc[dt];
  }
}

// ---- merge: combine chunk0 (raw in O) with chunk1 (ws partial) ----
__global__ __launch_bounds__(256) void merge_splits(char* __restrict__ ws,
                                                    float* __restrict__ O) {
  const int4* tab = (const int4*)(ws + TAB_OFF);
  if (!tab[0].z) return;
  const int splitcnt = tab[0].y;
  const int slot = blockIdx.x, h = blockIdx.y;
  if (slot >= splitcnt) return;
  const int* slot_r0 = (const int*)(ws + TAB_OFF + 129 * 16);
  const int r0 = slot_r0[slot];
  const int rl = threadIdx.x >> 2;           // 0..63
  const int d0 = (threadIdx.x & 3) * 32;     // 0,32,64,96
  const float* ml0 = (const float*)(ws + ML_OFF) +
                     (((size_t)slot * 16 + h) * 64 + rl) * 2;
  const float* ml1 = ml0 + ML_FLOATS_HALF;
  const float m0 = ml0[0], l0 = ml0[1], m1 = ml1[0], l1 = ml1[1];
  const float m = fmaxf(m0, m1);
  const float c0 = exp2f(m0 - m), c1 = exp2f(m1 - m);
  const float inv = 1.0f / (l0 * c0 + l1 * c1);
  float* op = &O[(size_t)(r0 + rl) * (NQH * HN) + h * HN + d0];
  const float* wp = (const float*)(ws + ACC_OFF) + (size_t)slot * SLOT_FLOATS +
                    ((size_t)h * 64 + rl) * HN + d0;
#pragma unroll
  for (int i = 0; i < 8; ++i) {
    f32x4 a = *(f32x4*)&op[i * 4];
    f32x4 b = *(const f32x4*)&wp[i * 4];
    f32x4 r = (a * c0 + b * c1) * inv;
    *(f32x4*)&op[i * 4] = r;
  }
}

extern "C" void kernel_launch(void* const* d_in, const int* in_sizes, int n_in,
                              void* d_out, int out_size, void* d_ws, size_t ws_size,
                              hipStream_t stream) {
  const float* Q = (const float*)d_in[0];
  const float* K = (const float*)d_in[1];
  const float* V = (const float*)d_in[2];
  const int* cu = (const int*)d_in[3];
  float* O = (float*)d_out;

  const int T = in_sizes[0] / (NQH * HN);  // 4096
  const int nseg = in_sizes[3] - 1;        // 4

  if (ws_size < STAGE_B + TAB_B) return;   // need staging + table minimum

  char* ws = (char*)d_ws;
  __bf16* Kb = (__bf16*)ws;
  __bf16* Vb = (__bf16*)ws + (size_t)NKH * T * HN;

  setup_units<<<1, 64, 0, stream>>>(cu, nseg, T, (unsigned long long)ws_size, ws);

  const int nelem = T * NKH * HN;
  cvt_k<<<nelem / 8 / 256, 256, 0, stream>>>(K, Kb, T);
  cvt_v<<<dim3(T / 8, NKH), 128, 0, stream>>>(V, Vb, T);

  attn_mfma6<<<dim3(2 * T / QBLK, NKH * 2), 512, 0, stream>>>(Q, Kb, Vb, ws, O, T);
  merge_splits<<<dim3(T / QBLK, NQH), 256, 0, stream>>>(ws, O);
}

// Round 9
// 124.217 us; speedup vs baseline: 1.2220x; 1.2220x over previous
//
#include <hip/hip_runtime.h>
#include <hip/hip_bf16.h>
#include <cstdint>
#include <cstddef>

#define NQH 16
#define NKH 4
#define HN 128
#define QBLK 64
#define KBLK 64
#define QSCALE 0.12751589542585458f  // (1/sqrt(128)) * log2(e)
#define TILEB 16384                  // KBLK*HN*2 bytes per K or V tile

// ---- workspace layout (bytes) ----
#define STAGE_B (8u << 20)                  // Kb(4MB) + Vb(4MB)
#define TAB_OFF STAGE_B                     // int4 hdr + int4 units[128] + slot_r0[64]
#define TAB_B 4096u
#define CTR_OFF (TAB_OFF + 3840u)           // 4B queue counter (memset per launch)
#define ML_OFF (TAB_OFF + TAB_B)
#define ML_FLOATS_HALF (64 * 16 * 64 * 2)   // per array: [slot][head][row][2]
#define ML_B (2u * ML_FLOATS_HALF * 4u)     // ml0 + ml1 = 1 MB
#define ACC_OFF (ML_OFF + ML_B)
#define SLOT_FLOATS (16 * 64 * 128)         // per split slot: [head][row][128]
#define SPLIT_MIN 13

typedef __bf16 bf16x8 __attribute__((ext_vector_type(8)));
typedef float f32x4 __attribute__((ext_vector_type(4)));

__device__ __forceinline__ void gload16(const void* g, void* l) {
  __builtin_amdgcn_global_load_lds(
      (const __attribute__((address_space(1))) void*)g,
      (__attribute__((address_space(3))) void*)l, 16, 0, 0);
}

// ---- setup: build LPT-sorted work-unit table (one 64-lane wave) ----
// unit = {r0, key_begin, key_end, mode | slot<<2}; mode 0=full 1=chunk0 2=chunk1
__global__ __launch_bounds__(64) void setup_units(const int* __restrict__ cu,
                                                  int nseg, int T,
                                                  unsigned long long cap,
                                                  char* __restrict__ ws) {
  __shared__ int e_len[128], e_r0[128], e_kb[128], e_ke[128], e_ms[128];
  int4* tab = (int4*)(ws + TAB_OFF);
  int* slot_r0 = (int*)(ws + TAB_OFF + 129 * 16);
  const int t = threadIdx.x;  // 0..63 = tile id
  const int r0 = t * QBLK;
  int st0 = 0;
  for (int s = 1; s < nseg; ++s) {
    const int c = cu[s];
    if (c <= r0) st0 = c;
  }
  const int kst = st0 & ~(KBLK - 1);
  const int nkb = (r0 + QBLK - kst) / KBLK;

  const unsigned long long bal = __ballot(nkb >= SPLIT_MIN);
  const int spl_total = __popcll(bal);
  const unsigned long long need =
      (unsigned long long)ACC_OFF + (unsigned long long)spl_total * SLOT_FLOATS * 4u;
  const int enabled = (need <= cap) ? 1 : 0;
  const int below = __popcll(bal & ((t == 0) ? 0ull : (~0ull >> (64 - t))));
  const int nu = 64 + (enabled ? spl_total : 0);
  const int base = t + (enabled ? below : 0);

  if (enabled && nkb >= SPLIT_MIN) {
    const int slot = below;
    const int h0 = (nkb + 1) >> 1;
    const int kmid = kst + h0 * KBLK;
    e_len[base] = h0; e_r0[base] = r0; e_kb[base] = kst;
    e_ke[base] = kmid; e_ms[base] = 1 | (slot << 2);
    e_len[base + 1] = nkb - h0; e_r0[base + 1] = r0; e_kb[base + 1] = kmid;
    e_ke[base + 1] = r0 + QBLK; e_ms[base + 1] = 2 | (slot << 2);
    slot_r0[slot] = r0;
  } else {
    e_len[base] = nkb; e_r0[base] = r0; e_kb[base] = kst;
    e_ke[base] = r0 + QBLK; e_ms[base] = 0;
  }
  __syncthreads();
  for (int i = t; i < nu; i += 64) {  // LPT rank: longest first
    const int li = e_len[i];
    int rk = 0;
    for (int j = 0; j < nu; ++j)
      rk += (e_len[j] > li) || (e_len[j] == li && j < i);
    tab[1 + rk] = make_int4(e_r0[i], e_kb[i], e_ke[i], e_ms[i]);
  }
  if (t == 0) tab[0] = make_int4(nu, enabled ? spl_total : 0, enabled, 0);
}

// ---- pre-kernel A: K f32 [T][4][128] -> Kb bf16 [4][T][128] ----
__global__ __launch_bounds__(256) void cvt_k(const float* __restrict__ K,
                                             __bf16* __restrict__ Kb, int T) {
  const size_t idx8 = ((size_t)blockIdx.x * 256 + threadIdx.x) * 8;
  const int d = (int)(idx8 & 127);
  const int kvh = (int)((idx8 >> 7) & 3);
  const size_t t = idx8 >> 9;
  float4 a = *(const float4*)&K[idx8];
  float4 b = *(const float4*)&K[idx8 + 4];
  bf16x8 f;
  f[0] = (__bf16)a.x; f[1] = (__bf16)a.y; f[2] = (__bf16)a.z; f[3] = (__bf16)a.w;
  f[4] = (__bf16)b.x; f[5] = (__bf16)b.y; f[6] = (__bf16)b.z; f[7] = (__bf16)b.w;
  *(bf16x8*)&Kb[(size_t)kvh * T * HN + t * HN + d] = f;
}

// ---- pre-kernel B: V f32 [T][4][128] -> Vb bf16 [4][128][T] (transposed) ----
__global__ __launch_bounds__(128) void cvt_v(const float* __restrict__ V,
                                             __bf16* __restrict__ Vb, int T) {
  const int d = threadIdx.x;
  const int t0 = blockIdx.x * 8;
  const int kvh = blockIdx.y;
  bf16x8 f;
#pragma unroll
  for (int i = 0; i < 8; ++i)
    f[i] = (__bf16)V[(size_t)(t0 + i) * (NKH * HN) + kvh * HN + d];
  *(bf16x8*)&Vb[(size_t)kvh * HN * T + (size_t)d * T + t0] = f;
}

// ---- one KV-block iteration: swapped MFMA, in-register P (permuted K rows) ----
template <bool MASKED>
__device__ __forceinline__ void attn_iter(const char* Kc, const char* Vc,
                                          const bf16x8 qf[4], int ln, int hi,
                                          int lim, float& m_, float& l_,
                                          f32x4* acc) {
  f32x4 sT[4];
#pragma unroll
  for (int c = 0; c < 4; ++c) sT[c] = (f32x4){0.f, 0.f, 0.f, 0.f};
  __builtin_amdgcn_s_setprio(1);
#pragma unroll
  for (int kc = 0; kc < 4; ++kc) {
#pragma unroll
    for (int c = 0; c < 4; ++c) {
      const int row = c * 16 + ln;
      const bf16x8 kf =
          *(const bf16x8*)(Kc + row * 256 + (((kc * 4 + hi) ^ (row & 7)) << 4));
      sT[c] = __builtin_amdgcn_mfma_f32_16x16x32_bf16(kf, qf[kc], sT[c], 0, 0, 0);
    }
  }
  __builtin_amdgcn_s_setprio(0);

  if (MASKED) {
#pragma unroll
    for (int c = 0; c < 4; ++c)
#pragma unroll
      for (int i = 0; i < 4; ++i) {
        const int koff = ((c >> 1) << 5) + hi * 8 + ((c & 1) << 2) + i;
        sT[c][i] = (koff <= lim) ? sT[c][i] : -1e30f;
      }
  }

  float mm = fmaxf(
      fmaxf(fmaxf(fmaxf(sT[0][0], sT[0][1]), fmaxf(sT[0][2], sT[0][3])),
            fmaxf(fmaxf(sT[1][0], sT[1][1]), fmaxf(sT[1][2], sT[1][3]))),
      fmaxf(fmaxf(fmaxf(sT[2][0], sT[2][1]), fmaxf(sT[2][2], sT[2][3])),
            fmaxf(fmaxf(sT[3][0], sT[3][1]), fmaxf(sT[3][2], sT[3][3]))));
  mm = fmaxf(mm, __shfl_xor(mm, 16));
  mm = fmaxf(mm, __shfl_xor(mm, 32));

  if (__any(mm > m_ + 8.0f)) {  // defer-max THR=8 (exp2 domain)
    const float mnew = fmaxf(m_, mm);
    const float corr = exp2f(m_ - mnew);
    m_ = mnew;
    l_ *= corr;
#pragma unroll
    for (int dt = 0; dt < 8; ++dt) acc[dt] *= corr;
  }

  float p[4][4];
  float ps = 0.f;
#pragma unroll
  for (int c = 0; c < 4; ++c)
#pragma unroll
    for (int i = 0; i < 4; ++i) {
      p[c][i] = exp2f(sT[c][i] - m_);
      ps += p[c][i];
    }
  ps += __shfl_xor(ps, 16);
  ps += __shfl_xor(ps, 32);
  l_ += ps;

  bf16x8 pa[2];
#pragma unroll
  for (int ch = 0; ch < 2; ++ch)
#pragma unroll
    for (int e = 0; e < 8; ++e)
      pa[ch][e] = (__bf16)p[2 * ch + (e >> 2)][e & 3];

  __builtin_amdgcn_s_setprio(1);
#pragma unroll
  for (int ch = 0; ch < 2; ++ch) {
#pragma unroll
    for (int dt = 0; dt < 8; ++dt) {
      const int vr = dt * 16 + ln;
      const bf16x8 vb =
          *(const bf16x8*)(Vc + vr * 128 + (((ch * 4 + hi) ^ (vr & 7)) << 4));
      acc[dt] = __builtin_amdgcn_mfma_f32_16x16x32_bf16(vb, pa[ch], acc[dt], 0, 0, 0);
    }
  }
  __builtin_amdgcn_s_setprio(0);
}

// ---- persistent main kernel: blocks pull LPT-sorted items from a queue ----
__global__ __launch_bounds__(512, 4) void attn_mfma7(
    const float* __restrict__ Q, const __bf16* __restrict__ Kb,
    const __bf16* __restrict__ Vb, char* __restrict__ ws,
    float* __restrict__ O, int T) {
  const int4* tab = (const int4*)(ws + TAB_OFF);
  int* ctr = (int*)(ws + CTR_OFF);
  const int nitems = tab[0].x * 8;  // item = rank*8 + y

  const int tid = threadIdx.x;
  const int w = tid >> 6, lane = tid & 63;
  const int wg = w >> 2, wl = w & 3;
  const int ln = lane & 15, hi = lane >> 4;

  __shared__ __bf16 K_lds[2][KBLK * HN];
  __shared__ __bf16 V_lds[2][HN * KBLK];
  __shared__ int s_item;

  // ---- loop-invariant staging offsets ----
  const int kR = w * 4 + hi;
  int keyoff[2];
#pragma unroll
  for (int j = 0; j < 2; ++j) {
    const int R = j * 32 + kR;
    const int c = R >> 4, r = R & 15;
    keyoff[j] = ((c >> 1) << 5) + ((r >> 2) << 3) + ((c & 1) << 2) + (r & 3);
  }
  const int kcol = ((ln ^ (kR & 7)) << 3);
  const int vrow = w * 8 + (lane >> 3);
  const int vcol = (((lane & 7) ^ ((lane >> 3) & 7)) << 3);
  char* ldsK0 = (char*)&K_lds[0][0] + w * 1024 + (size_t)lane * 16;
  char* ldsV0 = (char*)&V_lds[0][0] + w * 1024 + (size_t)lane * 16;

  for (;;) {
    if (tid == 0) s_item = atomicAdd(ctr, 1);
    __syncthreads();  // s_item visible; also guards LDS WAR vs previous item
    const int item = s_item;
    if (item >= nitems) break;  // uniform

    const int4 e = tab[1 + (item >> 3)];
    const int y = item & 7;
    const int r0 = e.x, kbeg = e.y, kend = e.z;
    const int mode = e.w & 3, slot = e.w >> 2;
    const int nloc = (kend - kbeg) / KBLK;
    const bool diag = (kend == r0 + QBLK);
    const int kvh = y >> 1;
    const int h = kvh * 4 + (y & 1) * 2 + wg;

    const __bf16* KbH = Kb + (size_t)kvh * T * HN;
    const __bf16* VbH = Vb + (size_t)kvh * HN * T;

    bf16x8 qf[4];
    {
      const float* qp = &Q[(size_t)(r0 + wl * 16 + ln) * (NQH * HN) + h * HN];
#pragma unroll
      for (int kc = 0; kc < 4; ++kc) {
        float4 a = *(const float4*)(qp + kc * 32 + hi * 8);
        float4 b = *(const float4*)(qp + kc * 32 + hi * 8 + 4);
        bf16x8 f;
        f[0] = (__bf16)(a.x * QSCALE); f[1] = (__bf16)(a.y * QSCALE);
        f[2] = (__bf16)(a.z * QSCALE); f[3] = (__bf16)(a.w * QSCALE);
        f[4] = (__bf16)(b.x * QSCALE); f[5] = (__bf16)(b.y * QSCALE);
        f[6] = (__bf16)(b.z * QSCALE); f[7] = (__bf16)(b.w * QSCALE);
        qf[kc] = f;
      }
    }

    float m_ = 0.f, l_ = 0.f;  // m starts at 0: rescale only if scores exceed +8
    f32x4 acc[8];
#pragma unroll
    for (int dt = 0; dt < 8; ++dt) acc[dt] = (f32x4){0.f, 0.f, 0.f, 0.f};

    // ---- prologue: stage tile 0 into buffer 0 ----
#pragma unroll
    for (int j = 0; j < 2; ++j)
      gload16(KbH + (size_t)(kbeg + keyoff[j]) * HN + kcol, ldsK0 + j * 8192);
#pragma unroll
    for (int j = 0; j < 2; ++j)
      gload16(VbH + (size_t)(j * 64 + vrow) * T + kbeg + vcol, ldsV0 + j * 8192);
    __syncthreads();

    for (int it = 0; it < nloc - 1; ++it) {
      const int cur = it & 1;
      const int kn = kbeg + (it + 1) * KBLK;
      char* dK = ldsK0 + (cur ^ 1) * TILEB;
      char* dV = ldsV0 + (cur ^ 1) * TILEB;
#pragma unroll
      for (int j = 0; j < 2; ++j)
        gload16(KbH + (size_t)(kn + keyoff[j]) * HN + kcol, dK + j * 8192);
#pragma unroll
      for (int j = 0; j < 2; ++j)
        gload16(VbH + (size_t)(j * 64 + vrow) * T + kn + vcol, dV + j * 8192);

      attn_iter<false>((const char*)&K_lds[0][0] + cur * TILEB,
                       (const char*)&V_lds[0][0] + cur * TILEB, qf, ln, hi, 0,
                       m_, l_, acc);
      __syncthreads();
    }
    {
      const int cur = (nloc - 1) & 1;
      const char* Kc = (const char*)&K_lds[0][0] + cur * TILEB;
      const char* Vc = (const char*)&V_lds[0][0] + cur * TILEB;
      if (diag)
        attn_iter<true>(Kc, Vc, qf, ln, hi, wl * 16 + ln, m_, l_, acc);
      else
        attn_iter<false>(Kc, Vc, qf, ln, hi, 0, m_, l_, acc);
    }

    const int rowl = wl * 16 + ln;
    if (mode == 0) {
      const float inv = 1.0f / l_;
      float* op = &O[(size_t)(r0 + rowl) * (NQH * HN) + h * HN];
#pragma unroll
      for (int dt = 0; dt < 8; ++dt) {
        f32x4 res = acc[dt] * inv;
        *(f32x4*)&op[dt * 16 + hi * 4] = res;
      }
    } else {
      float* mlb = (float*)(ws + ML_OFF) + (mode == 2 ? ML_FLOATS_HALF : 0);
      if (hi == 0) {
        float* ml = mlb + (((size_t)slot * 16 + h) * 64 + rowl) * 2;
        ml[0] = m_; ml[1] = l_;
      }
      float* dst = (mode == 1)
                       ? &O[(size_t)(r0 + rowl) * (NQH * HN) + h * HN]
                       : (float*)(ws + ACC_OFF) + (size_t)slot * SLOT_FLOATS +
                             ((size_t)h * 64 + rowl) * HN;
#pragma unroll
      for (int dt = 0; dt < 8; ++dt) *(f32x4*)&dst[dt * 16 + hi * 4] = acc[dt];
    }
    // next loop's barrier (after atomicAdd) guards LDS/s_item reuse
  }
}

// ---- merge: combine chunk0 (raw in O) with chunk1 (ws partial) ----
__global__ __launch_bounds__(256) void merge_splits(char* __restrict__ ws,
                                                    float* __restrict__ O) {
  const int4* tab = (const int4*)(ws + TAB_OFF);
  if (!tab[0].z) return;
  const int splitcnt = tab[0].y;
  const int slot = blockIdx.x, h = blockIdx.y;
  if (slot >= splitcnt) return;
  const int* slot_r0 = (const int*)(ws + TAB_OFF + 129 * 16);
  const int r0 = slot_r0[slot];
  const int rl = threadIdx.x >> 2;
  const int d0 = (threadIdx.x & 3) * 32;
  const float* ml0 = (const float*)(ws + ML_OFF) +
                     (((size_t)slot * 16 + h) * 64 + rl) * 2;
  const float* ml1 = ml0 + ML_FLOATS_HALF;
  const float m0 = ml0[0], l0 = ml0[1], m1 = ml1[0], l1 = ml1[1];
  const float m = fmaxf(m0, m1);
  const float c0 = exp2f(m0 - m), c1 = exp2f(m1 - m);
  const float inv = 1.0f / (l0 * c0 + l1 * c1);
  float* op = &O[(size_t)(r0 + rl) * (NQH * HN) + h * HN + d0];
  const float* wp = (const float*)(ws + ACC_OFF) + (size_t)slot * SLOT_FLOATS +
                    ((size_t)h * 64 + rl) * HN + d0;
#pragma unroll
  for (int i = 0; i < 8; ++i) {
    f32x4 a = *(f32x4*)&op[i * 4];
    f32x4 b = *(const f32x4*)&wp[i * 4];
    f32x4 r = (a * c0 + b * c1) * inv;
    *(f32x4*)&op[i * 4] = r;
  }
}

extern "C" void kernel_launch(void* const* d_in, const int* in_sizes, int n_in,
                              void* d_out, int out_size, void* d_ws, size_t ws_size,
                              hipStream_t stream) {
  const float* Q = (const float*)d_in[0];
  const float* K = (const float*)d_in[1];
  const float* V = (const float*)d_in[2];
  const int* cu = (const int*)d_in[3];
  float* O = (float*)d_out;

  const int T = in_sizes[0] / (NQH * HN);  // 4096
  const int nseg = in_sizes[3] - 1;        // 4

  if (ws_size < STAGE_B + TAB_B) return;

  char* ws = (char*)d_ws;
  __bf16* Kb = (__bf16*)ws;
  __bf16* Vb = (__bf16*)ws + (size_t)NKH * T * HN;

  hipMemsetAsync(ws + CTR_OFF, 0, 4, stream);  // zero queue counter
  setup_units<<<1, 64, 0, stream>>>(cu, nseg, T, (unsigned long long)ws_size, ws);

  const int nelem = T * NKH * HN;
  cvt_k<<<nelem / 8 / 256, 256, 0, stream>>>(K, Kb, T);
  cvt_v<<<dim3(T / 8, NKH), 128, 0, stream>>>(V, Vb, T);

  attn_mfma7<<<512, 512, 0, stream>>>(Q, Kb, Vb, ws, O, T);
  merge_splits<<<dim3(T / QBLK, NQH), 256, 0, stream>>>(ws, O);
}

// Round 10
// 79.459 us; speedup vs baseline: 1.9103x; 1.5633x over previous
//
#include <hip/hip_runtime.h>
#include <hip/hip_bf16.h>
#include <cstdint>
#include <cstddef>

#define NQH 16
#define NKH 4
#define HN 128
#define QBLK 128                     // rows per block (4 waves x 32 rows)
#define KBLK 64
#define QSCALE 0.12751589542585458f  // (1/sqrt(128)) * log2(e)
#define TILEB 16384                  // KBLK*HN*2 bytes per K or V tile

typedef __bf16 bf16x8 __attribute__((ext_vector_type(8)));
typedef float f32x4 __attribute__((ext_vector_type(4)));

__device__ __forceinline__ void gload16(const void* g, void* l) {
  __builtin_amdgcn_global_load_lds(
      (const __attribute__((address_space(1))) void*)g,
      (__attribute__((address_space(3))) void*)l, 16, 0, 0);
}

// ---- pre-kernel A: K f32 [T][4][128] -> Kb bf16 [4][T][128] ----
__global__ __launch_bounds__(256) void cvt_k(const float* __restrict__ K,
                                             __bf16* __restrict__ Kb, int T) {
  const size_t idx8 = ((size_t)blockIdx.x * 256 + threadIdx.x) * 8;
  const int d = (int)(idx8 & 127);
  const int kvh = (int)((idx8 >> 7) & 3);
  const size_t t = idx8 >> 9;
  float4 a = *(const float4*)&K[idx8];
  float4 b = *(const float4*)&K[idx8 + 4];
  bf16x8 f;
  f[0] = (__bf16)a.x; f[1] = (__bf16)a.y; f[2] = (__bf16)a.z; f[3] = (__bf16)a.w;
  f[4] = (__bf16)b.x; f[5] = (__bf16)b.y; f[6] = (__bf16)b.z; f[7] = (__bf16)b.w;
  *(bf16x8*)&Kb[(size_t)kvh * T * HN + t * HN + d] = f;
}

// ---- pre-kernel B: V f32 [T][4][128] -> Vb bf16 [4][128][T] (transposed) ----
__global__ __launch_bounds__(128) void cvt_v(const float* __restrict__ V,
                                             __bf16* __restrict__ Vb, int T) {
  const int d = threadIdx.x;
  const int t0 = blockIdx.x * 8;
  const int kvh = blockIdx.y;
  bf16x8 f;
#pragma unroll
  for (int i = 0; i < 8; ++i)
    f[i] = (__bf16)V[(size_t)(t0 + i) * (NKH * HN) + kvh * HN + d];
  *(bf16x8*)&Vb[(size_t)kvh * HN * T + (size_t)d * T + t0] = f;
}

// ---- one KV-block: swapped MFMA, TWO q-sets share all K/V ds_reads ----
// Lane set A owns q-row rel = wl*32 + ln, set B = +16.
// sX[c][i] = S[q][kb + koff], koff = (c>>1)*32 + hi*8 + (c&1)*4 + i.
template <bool MASKED>
__device__ __forceinline__ void attn_iter(
    const char* Kc, const char* Vc, const bf16x8 qfA[4], const bf16x8 qfB[4],
    int ln, int hi, int limA, float& mA, float& lA, f32x4* accA,
    float& mB, float& lB, f32x4* accB) {
  f32x4 sA[4], sB[4];
#pragma unroll
  for (int c = 0; c < 4; ++c) {
    sA[c] = (f32x4){0.f, 0.f, 0.f, 0.f};
    sB[c] = (f32x4){0.f, 0.f, 0.f, 0.f};
  }
  __builtin_amdgcn_s_setprio(1);
#pragma unroll
  for (int kc = 0; kc < 4; ++kc) {
#pragma unroll
    for (int c = 0; c < 4; ++c) {
      const int row = c * 16 + ln;
      const bf16x8 kf =
          *(const bf16x8*)(Kc + row * 256 + (((kc * 4 + hi) ^ (row & 7)) << 4));
      sA[c] = __builtin_amdgcn_mfma_f32_16x16x32_bf16(kf, qfA[kc], sA[c], 0, 0, 0);
      sB[c] = __builtin_amdgcn_mfma_f32_16x16x32_bf16(kf, qfB[kc], sB[c], 0, 0, 0);
    }
  }
  __builtin_amdgcn_s_setprio(0);

  if (MASKED) {
    const int limB = limA + 16;
#pragma unroll
    for (int c = 0; c < 4; ++c)
#pragma unroll
      for (int i = 0; i < 4; ++i) {
        const int koff = ((c >> 1) << 5) + hi * 8 + ((c & 1) << 2) + i;
        sA[c][i] = (koff <= limA) ? sA[c][i] : -1e30f;
        sB[c][i] = (koff <= limB) ? sB[c][i] : -1e30f;
      }
  }

  float mmA = fmaxf(
      fmaxf(fmaxf(fmaxf(sA[0][0], sA[0][1]), fmaxf(sA[0][2], sA[0][3])),
            fmaxf(fmaxf(sA[1][0], sA[1][1]), fmaxf(sA[1][2], sA[1][3]))),
      fmaxf(fmaxf(fmaxf(sA[2][0], sA[2][1]), fmaxf(sA[2][2], sA[2][3])),
            fmaxf(fmaxf(sA[3][0], sA[3][1]), fmaxf(sA[3][2], sA[3][3]))));
  float mmB = fmaxf(
      fmaxf(fmaxf(fmaxf(sB[0][0], sB[0][1]), fmaxf(sB[0][2], sB[0][3])),
            fmaxf(fmaxf(sB[1][0], sB[1][1]), fmaxf(sB[1][2], sB[1][3]))),
      fmaxf(fmaxf(fmaxf(sB[2][0], sB[2][1]), fmaxf(sB[2][2], sB[2][3])),
            fmaxf(fmaxf(sB[3][0], sB[3][1]), fmaxf(sB[3][2], sB[3][3]))));
  mmA = fmaxf(mmA, __shfl_xor(mmA, 16));
  mmA = fmaxf(mmA, __shfl_xor(mmA, 32));
  mmB = fmaxf(mmB, __shfl_xor(mmB, 16));
  mmB = fmaxf(mmB, __shfl_xor(mmB, 32));

  if (__any((mmA > mA + 8.0f) | (mmB > mB + 8.0f))) {  // defer-max THR=8
    const float mnA = fmaxf(mA, mmA), mnB = fmaxf(mB, mmB);
    const float cA = exp2f(mA - mnA), cB = exp2f(mB - mnB);
    mA = mnA; mB = mnB;
    lA *= cA; lB *= cB;
#pragma unroll
    for (int dt = 0; dt < 8; ++dt) { accA[dt] *= cA; accB[dt] *= cB; }
  }

  float pA[4][4], pB[4][4];
  float psA = 0.f, psB = 0.f;
#pragma unroll
  for (int c = 0; c < 4; ++c)
#pragma unroll
    for (int i = 0; i < 4; ++i) {
      pA[c][i] = exp2f(sA[c][i] - mA); psA += pA[c][i];
      pB[c][i] = exp2f(sB[c][i] - mB); psB += pB[c][i];
    }
  psA += __shfl_xor(psA, 16); psA += __shfl_xor(psA, 32);
  psB += __shfl_xor(psB, 16); psB += __shfl_xor(psB, 32);
  lA += psA; lB += psB;

  bf16x8 paA[2], paB[2];
#pragma unroll
  for (int ch = 0; ch < 2; ++ch)
#pragma unroll
    for (int e = 0; e < 8; ++e) {
      paA[ch][e] = (__bf16)pA[2 * ch + (e >> 2)][e & 3];
      paB[ch][e] = (__bf16)pB[2 * ch + (e >> 2)][e & 3];
    }

  __builtin_amdgcn_s_setprio(1);
#pragma unroll
  for (int ch = 0; ch < 2; ++ch) {
#pragma unroll
    for (int dt = 0; dt < 8; ++dt) {
      const int vr = dt * 16 + ln;
      const bf16x8 vb =
          *(const bf16x8*)(Vc + vr * 128 + (((ch * 4 + hi) ^ (vr & 7)) << 4));
      accA[dt] = __builtin_amdgcn_mfma_f32_16x16x32_bf16(vb, paA[ch], accA[dt], 0, 0, 0);
      accB[dt] = __builtin_amdgcn_mfma_f32_16x16x32_bf16(vb, paB[ch], accB[dt], 0, 0, 0);
    }
  }
  __builtin_amdgcn_s_setprio(0);
}

// ---- main: 4 waves x 32 rows = 128-row tile, 1 head; rank-paired schedule ----
__global__ __launch_bounds__(256, 2) void attn_mfma8(
    const float* __restrict__ Q, const __bf16* __restrict__ Kb,
    const __bf16* __restrict__ Vb, const int* __restrict__ cu,
    float* __restrict__ O, int T, int nseg) {
  const int tid = threadIdx.x;
  const int w = tid >> 6, lane = tid & 63;
  const int ln = lane & 15, hi = lane >> 4;
  const int h = blockIdx.y;        // head 0..15
  const int kvh = h >> 2;

  __shared__ __bf16 K_lds[2][KBLK * HN];  // 2 x 16 KB
  __shared__ __bf16 V_lds[2][HN * KBLK];  // 2 x 16 KB
  __shared__ int s_tile;

  // ---- pick tile by depth-rank: first dispatch round heavy, second light ----
  // blocks c and c+256 co-reside on a CU (round-robin heuristic): give them
  // complementary ranks so per-CU work ~ constant.
  {
    const int my_rank = (h < 8) ? (int)blockIdx.x : 31 - (int)blockIdx.x;
    if (w == 0) {
      const int t2 = lane & 31;
      const int r0t = t2 << 7;
      int st = 0;
      for (int s = 1; s < nseg; ++s) {
        const int c = cu[s];
        if (c <= r0t) st = c;
      }
      const int dep = r0t + 128 - st;
      int rk = 0;
      for (int j = 0; j < 32; ++j) {
        const int dj = __shfl(dep, j);
        rk += (dj > dep) || (dj == dep && j < t2);
      }
      if (lane < 32 && rk == my_rank) s_tile = t2;
    }
    __syncthreads();
  }
  const int tile = s_tile;
  const int r0 = tile << 7;

  int st0 = 0;
  for (int s = 1; s < nseg; ++s) {
    const int c = cu[s];
    if (c <= r0) st0 = c;
  }
  const int kstart = st0 & ~(KBLK - 1);
  const int nloc = (r0 + QBLK - kstart) / KBLK;

  const __bf16* KbH = Kb + (size_t)kvh * T * HN;
  const __bf16* VbH = Vb + (size_t)kvh * HN * T;

  // ---- Q fragments: two row-sets, scaled ----
  bf16x8 qfA[4], qfB[4];
  {
    const float* qpA = &Q[(size_t)(r0 + w * 32 + ln) * (NQH * HN) + h * HN];
    const float* qpB = qpA + (size_t)16 * (NQH * HN);
#pragma unroll
    for (int kc = 0; kc < 4; ++kc) {
      float4 a0 = *(const float4*)(qpA + kc * 32 + hi * 8);
      float4 a1 = *(const float4*)(qpA + kc * 32 + hi * 8 + 4);
      float4 b0 = *(const float4*)(qpB + kc * 32 + hi * 8);
      float4 b1 = *(const float4*)(qpB + kc * 32 + hi * 8 + 4);
      bf16x8 fa, fb;
      fa[0] = (__bf16)(a0.x * QSCALE); fa[1] = (__bf16)(a0.y * QSCALE);
      fa[2] = (__bf16)(a0.z * QSCALE); fa[3] = (__bf16)(a0.w * QSCALE);
      fa[4] = (__bf16)(a1.x * QSCALE); fa[5] = (__bf16)(a1.y * QSCALE);
      fa[6] = (__bf16)(a1.z * QSCALE); fa[7] = (__bf16)(a1.w * QSCALE);
      fb[0] = (__bf16)(b0.x * QSCALE); fb[1] = (__bf16)(b0.y * QSCALE);
      fb[2] = (__bf16)(b0.z * QSCALE); fb[3] = (__bf16)(b0.w * QSCALE);
      fb[4] = (__bf16)(b1.x * QSCALE); fb[5] = (__bf16)(b1.y * QSCALE);
      fb[6] = (__bf16)(b1.z * QSCALE); fb[7] = (__bf16)(b1.w * QSCALE);
      qfA[kc] = fa; qfB[kc] = fb;
    }
  }

  float mA = 0.f, lA = 0.f, mB = 0.f, lB = 0.f;
  f32x4 accA[8], accB[8];
#pragma unroll
  for (int dt = 0; dt < 8; ++dt) {
    accA[dt] = (f32x4){0.f, 0.f, 0.f, 0.f};
    accB[dt] = (f32x4){0.f, 0.f, 0.f, 0.f};
  }

  // ---- staging invariants (4 waves: 8 x 16B per lane per tile-pair) ----
  // K round j(0..3): row R = j*16 + w*4 + hi holds key kb + sigma(R), slot ln
  const int kR = w * 4 + hi;
  int keyoff[4];
#pragma unroll
  for (int j = 0; j < 4; ++j) {
    const int R = j * 16 + kR;
    const int c = R >> 4, r = R & 15;
    keyoff[j] = ((c >> 1) << 5) + ((r >> 2) << 3) + ((c & 1) << 2) + (r & 3);
  }
  const int kcol = ((ln ^ (kR & 7)) << 3);
  // V round j(0..3): row d = j*32 + w*8 + (lane>>3), slot lane&7
  const int vrow = w * 8 + (lane >> 3);
  const int vcol = (((lane & 7) ^ ((lane >> 3) & 7)) << 3);
  char* ldsK0 = (char*)&K_lds[0][0] + w * 1024 + (size_t)lane * 16;
  char* ldsV0 = (char*)&V_lds[0][0] + w * 1024 + (size_t)lane * 16;

  // ---- prologue: stage tile 0 ----
#pragma unroll
  for (int j = 0; j < 4; ++j)
    gload16(KbH + (size_t)(kstart + keyoff[j]) * HN + kcol, ldsK0 + j * 4096);
#pragma unroll
  for (int j = 0; j < 4; ++j)
    gload16(VbH + (size_t)(j * 32 + vrow) * T + kstart + vcol, ldsV0 + j * 4096);
  __syncthreads();

  const int relA = w * 32 + ln;  // set A row within tile
  for (int it = 0; it < nloc; ++it) {
    const int kb = kstart + it * KBLK;
    const int cur = it & 1;
    if (it + 1 < nloc) {  // prefetch next
      const int kn = kb + KBLK;
      char* dK = ldsK0 + (cur ^ 1) * TILEB;
      char* dV = ldsV0 + (cur ^ 1) * TILEB;
#pragma unroll
      for (int j = 0; j < 4; ++j)
        gload16(KbH + (size_t)(kn + keyoff[j]) * HN + kcol, dK + j * 4096);
#pragma unroll
      for (int j = 0; j < 4; ++j)
        gload16(VbH + (size_t)(j * 32 + vrow) * T + kn + vcol, dV + j * 4096);
    }
    const char* Kc = (const char*)&K_lds[0][0] + cur * TILEB;
    const char* Vc = (const char*)&V_lds[0][0] + cur * TILEB;
    if (kb >= r0)  // diagonal region (last two iters): causal mask
      attn_iter<true>(Kc, Vc, qfA, qfB, ln, hi, relA - (kb - r0), mA, lA, accA,
                      mB, lB, accB);
    else
      attn_iter<false>(Kc, Vc, qfA, qfB, ln, hi, 0, mA, lA, accA, mB, lB, accB);
    __syncthreads();
  }

  // ---- epilogue ----
  const float invA = 1.0f / lA, invB = 1.0f / lB;
  float* opA = &O[(size_t)(r0 + w * 32 + ln) * (NQH * HN) + h * HN];
  float* opB = opA + (size_t)16 * (NQH * HN);
#pragma unroll
  for (int dt = 0; dt < 8; ++dt) {
    f32x4 ra = accA[dt] * invA;
    f32x4 rb = accB[dt] * invB;
    *(f32x4*)&opA[dt * 16 + hi * 4] = ra;
    *(f32x4*)&opB[dt * 16 + hi * 4] = rb;
  }
}

extern "C" void kernel_launch(void* const* d_in, const int* in_sizes, int n_in,
                              void* d_out, int out_size, void* d_ws, size_t ws_size,
                              hipStream_t stream) {
  const float* Q = (const float*)d_in[0];
  const float* K = (const float*)d_in[1];
  const float* V = (const float*)d_in[2];
  const int* cu = (const int*)d_in[3];
  float* O = (float*)d_out;

  const int T = in_sizes[0] / (NQH * HN);  // 4096
  const int nseg = in_sizes[3] - 1;        // 4

  const size_t need = (size_t)2 * NKH * T * HN * sizeof(__bf16);  // 8 MB
  if (ws_size < need) return;

  __bf16* Kb = (__bf16*)d_ws;
  __bf16* Vb = (__bf16*)d_ws + (size_t)NKH * T * HN;

  const int nelem = T * NKH * HN;
  cvt_k<<<nelem / 8 / 256, 256, 0, stream>>>(K, Kb, T);
  cvt_v<<<dim3(T / 8, NKH), 128, 0, stream>>>(V, Vb, T);

  dim3 grid(T / QBLK, NQH);  // 32 tiles x 16 heads = 512 blocks
  attn_mfma8<<<grid, 256, 0, stream>>>(Q, Kb, Vb, cu, O, T, nseg);
}

// Round 12
// 69.358 us; speedup vs baseline: 2.1886x; 1.1456x over previous
//
#include <hip/hip_runtime.h>
#include <hip/hip_bf16.h>
#include <cstdint>
#include <cstddef>

#define NQH 16
#define NKH 4
#define HN 128
#define QBLK 64                      // rows per tile (2 waves x 32 rows)
#define KBLK 64
#define QSCALE 0.12751589542585458f  // (1/sqrt(128)) * log2(e)

typedef __bf16 bf16x8 __attribute__((ext_vector_type(8)));
typedef float f32x4 __attribute__((ext_vector_type(4)));

__device__ __forceinline__ void gload16(const void* g, void* l) {
  __builtin_amdgcn_global_load_lds(
      (const __attribute__((address_space(1))) void*)g,
      (__attribute__((address_space(3))) void*)l, 16, 0, 0);
}

// ---- pre-kernel A: K f32 [T][4][128] -> Kb bf16 [4][T][128] ----
__global__ __launch_bounds__(256) void cvt_k(const float* __restrict__ K,
                                             __bf16* __restrict__ Kb, int T) {
  const size_t idx8 = ((size_t)blockIdx.x * 256 + threadIdx.x) * 8;
  const int d = (int)(idx8 & 127);
  const int kvh = (int)((idx8 >> 7) & 3);
  const size_t t = idx8 >> 9;
  float4 a = *(const float4*)&K[idx8];
  float4 b = *(const float4*)&K[idx8 + 4];
  bf16x8 f;
  f[0] = (__bf16)a.x; f[1] = (__bf16)a.y; f[2] = (__bf16)a.z; f[3] = (__bf16)a.w;
  f[4] = (__bf16)b.x; f[5] = (__bf16)b.y; f[6] = (__bf16)b.z; f[7] = (__bf16)b.w;
  *(bf16x8*)&Kb[(size_t)kvh * T * HN + t * HN + d] = f;
}

// ---- pre-kernel B: V f32 [T][4][128] -> Vb bf16 [4][128][T] (transposed) ----
__global__ __launch_bounds__(128) void cvt_v(const float* __restrict__ V,
                                             __bf16* __restrict__ Vb, int T) {
  const int d = threadIdx.x;
  const int t0 = blockIdx.x * 8;
  const int kvh = blockIdx.y;
  bf16x8 f;
#pragma unroll
  for (int i = 0; i < 8; ++i)
    f[i] = (__bf16)V[(size_t)(t0 + i) * (NKH * HN) + kvh * HN + d];
  *(bf16x8*)&Vb[(size_t)kvh * HN * T + (size_t)d * T + t0] = f;
}

// ---- one KV-block: swapped MFMA, two q-row-sets share all K/V ds_reads ----
// sX[c][i] = S[q][kb + koff], koff = (c>>1)*32 + hi*8 + (c&1)*4 + i.
template <bool MASKED>
__device__ __forceinline__ void attn_iter(
    const char* Kc, const char* Vc, const bf16x8 qfA[4], const bf16x8 qfB[4],
    int ln, int hi, int limA, float& mA, float& lA, f32x4* accA,
    float& mB, float& lB, f32x4* accB) {
  f32x4 sA[4], sB[4];
#pragma unroll
  for (int c = 0; c < 4; ++c) {
    sA[c] = (f32x4){0.f, 0.f, 0.f, 0.f};
    sB[c] = (f32x4){0.f, 0.f, 0.f, 0.f};
  }
  __builtin_amdgcn_s_setprio(1);
#pragma unroll
  for (int kc = 0; kc < 4; ++kc) {
#pragma unroll
    for (int c = 0; c < 4; ++c) {
      const int row = c * 16 + ln;
      const bf16x8 kf =
          *(const bf16x8*)(Kc + row * 256 + (((kc * 4 + hi) ^ (row & 7)) << 4));
      sA[c] = __builtin_amdgcn_mfma_f32_16x16x32_bf16(kf, qfA[kc], sA[c], 0, 0, 0);
      sB[c] = __builtin_amdgcn_mfma_f32_16x16x32_bf16(kf, qfB[kc], sB[c], 0, 0, 0);
    }
  }
  __builtin_amdgcn_s_setprio(0);

  if (MASKED) {
    const int limB = limA + 16;
#pragma unroll
    for (int c = 0; c < 4; ++c)
#pragma unroll
      for (int i = 0; i < 4; ++i) {
        const int koff = ((c >> 1) << 5) + hi * 8 + ((c & 1) << 2) + i;
        sA[c][i] = (koff <= limA) ? sA[c][i] : -1e30f;
        sB[c][i] = (koff <= limB) ? sB[c][i] : -1e30f;
      }
  }

  float mmA = fmaxf(
      fmaxf(fmaxf(fmaxf(sA[0][0], sA[0][1]), fmaxf(sA[0][2], sA[0][3])),
            fmaxf(fmaxf(sA[1][0], sA[1][1]), fmaxf(sA[1][2], sA[1][3]))),
      fmaxf(fmaxf(fmaxf(sA[2][0], sA[2][1]), fmaxf(sA[2][2], sA[2][3])),
            fmaxf(fmaxf(sA[3][0], sA[3][1]), fmaxf(sA[3][2], sA[3][3]))));
  float mmB = fmaxf(
      fmaxf(fmaxf(fmaxf(sB[0][0], sB[0][1]), fmaxf(sB[0][2], sB[0][3])),
            fmaxf(fmaxf(sB[1][0], sB[1][1]), fmaxf(sB[1][2], sB[1][3]))),
      fmaxf(fmaxf(fmaxf(sB[2][0], sB[2][1]), fmaxf(sB[2][2], sB[2][3])),
            fmaxf(fmaxf(sB[3][0], sB[3][1]), fmaxf(sB[3][2], sB[3][3]))));
  mmA = fmaxf(mmA, __shfl_xor(mmA, 16));
  mmA = fmaxf(mmA, __shfl_xor(mmA, 32));
  mmB = fmaxf(mmB, __shfl_xor(mmB, 16));
  mmB = fmaxf(mmB, __shfl_xor(mmB, 32));

  if (__any((mmA > mA + 8.0f) | (mmB > mB + 8.0f))) {  // defer-max THR=8
    const float mnA = fmaxf(mA, mmA), mnB = fmaxf(mB, mmB);
    const float cA = exp2f(mA - mnA), cB = exp2f(mB - mnB);
    mA = mnA; mB = mnB;
    lA *= cA; lB *= cB;
#pragma unroll
    for (int dt = 0; dt < 8; ++dt) { accA[dt] *= cA; accB[dt] *= cB; }
  }

  float pA[4][4], pB[4][4];
  float psA = 0.f, psB = 0.f;
#pragma unroll
  for (int c = 0; c < 4; ++c)
#pragma unroll
    for (int i = 0; i < 4; ++i) {
      pA[c][i] = exp2f(sA[c][i] - mA); psA += pA[c][i];
      pB[c][i] = exp2f(sB[c][i] - mB); psB += pB[c][i];
    }
  psA += __shfl_xor(psA, 16); psA += __shfl_xor(psA, 32);
  psB += __shfl_xor(psB, 16); psB += __shfl_xor(psB, 32);
  lA += psA; lB += psB;

  bf16x8 paA[2], paB[2];
#pragma unroll
  for (int ch = 0; ch < 2; ++ch)
#pragma unroll
    for (int e = 0; e < 8; ++e) {
      paA[ch][e] = (__bf16)pA[2 * ch + (e >> 2)][e & 3];
      paB[ch][e] = (__bf16)pB[2 * ch + (e >> 2)][e & 3];
    }

  __builtin_amdgcn_s_setprio(1);
#pragma unroll
  for (int ch = 0; ch < 2; ++ch) {
#pragma unroll
    for (int dt = 0; dt < 8; ++dt) {
      const int vr = dt * 16 + ln;
      const bf16x8 vb =
          *(const bf16x8*)(Vc + vr * 128 + (((ch * 4 + hi) ^ (vr & 7)) << 4));
      accA[dt] = __builtin_amdgcn_mfma_f32_16x16x32_bf16(vb, paA[ch], accA[dt], 0, 0, 0);
      accB[dt] = __builtin_amdgcn_mfma_f32_16x16x32_bf16(vb, paB[ch], accB[dt], 0, 0, 0);
    }
  }
  __builtin_amdgcn_s_setprio(0);
}

// ---- main: 4 waves (256 thr) = 2 K-chunk groups x (2 waves x 32 rows) ----
// blockIdx.x = rank*16 + head; tile-rank 0 = deepest tile (hardware-LPT refill)
__global__ __launch_bounds__(256, 2) void attn_mfma9(
    const float* __restrict__ Q, const __bf16* __restrict__ Kb,
    const __bf16* __restrict__ Vb, const int* __restrict__ cu,
    float* __restrict__ O, int T, int nseg) {
  const int tid = threadIdx.x;
  const int w = tid >> 6, lane = tid & 63;   // w in 0..3
  const int g = w >> 1, wv = w & 1;          // K-chunk group (0,1), wave-in-group
  const int ln = lane & 15, hi = lane >> 4;
  const int h = blockIdx.x & 15;
  const int my_rank = blockIdx.x >> 4;       // tile depth-rank
  const int kvh = h >> 2;

  __shared__ __bf16 K_lds[2][KBLK * HN];     // per-group K tile (16 KB each)
  __shared__ __bf16 V_lds[2][HN * KBLK];     // per-group V tile (16 KB each)
  __shared__ float ml1[QBLK][2];             // group1 (m, l) per row
  __shared__ int s_tile;

  // ---- tile select: wave 0 ranks the 64 tiles by depth desc ----
  if (w == 0) {
    const int t2 = lane;                     // tile id 0..63
    const int r0t = t2 << 6;
    int st = 0;
    for (int s = 1; s < nseg; ++s) { const int c = cu[s]; if (c <= r0t) st = c; }
    const int dep = r0t + QBLK - st;
    int rk = 0;
    for (int j = 0; j < 64; ++j) {
      const int dj = __shfl(dep, j);
      rk += (dj > dep) || (dj == dep && j < t2);
    }
    if (rk == my_rank) s_tile = t2;
  }
  __syncthreads();
  const int r0 = s_tile << 6;

  int st0 = 0;
  for (int s = 1; s < nseg; ++s) { const int c = cu[s]; if (c <= r0) st0 = c; }
  const int kstart = st0;                    // cu values are 64-aligned
  const int nloc = (r0 + QBLK - kstart) >> 6;
  const int n0 = (nloc + 1) >> 1;
  const int myn = g ? (nloc - n0) : n0;      // group1 may be shorter (or 0)
  const int gbeg = kstart + (g ? n0 * KBLK : 0);

  const __bf16* KbH = Kb + (size_t)kvh * T * HN;
  const __bf16* VbH = Vb + (size_t)kvh * HN * T;

  // ---- Q fragments: rows r0 + wv*32 + ln (set A), +16 (set B) ----
  bf16x8 qfA[4], qfB[4];
  {
    const float* qpA = &Q[(size_t)(r0 + wv * 32 + ln) * (NQH * HN) + h * HN];
    const float* qpB = qpA + (size_t)16 * (NQH * HN);
#pragma unroll
    for (int kc = 0; kc < 4; ++kc) {
      float4 a0 = *(const float4*)(qpA + kc * 32 + hi * 8);
      float4 a1 = *(const float4*)(qpA + kc * 32 + hi * 8 + 4);
      float4 b0 = *(const float4*)(qpB + kc * 32 + hi * 8);
      float4 b1 = *(const float4*)(qpB + kc * 32 + hi * 8 + 4);
      bf16x8 fa, fb;
      fa[0] = (__bf16)(a0.x * QSCALE); fa[1] = (__bf16)(a0.y * QSCALE);
      fa[2] = (__bf16)(a0.z * QSCALE); fa[3] = (__bf16)(a0.w * QSCALE);
      fa[4] = (__bf16)(a1.x * QSCALE); fa[5] = (__bf16)(a1.y * QSCALE);
      fa[6] = (__bf16)(a1.z * QSCALE); fa[7] = (__bf16)(a1.w * QSCALE);
      fb[0] = (__bf16)(b0.x * QSCALE); fb[1] = (__bf16)(b0.y * QSCALE);
      fb[2] = (__bf16)(b0.z * QSCALE); fb[3] = (__bf16)(b0.w * QSCALE);
      fb[4] = (__bf16)(b1.x * QSCALE); fb[5] = (__bf16)(b1.y * QSCALE);
      fb[6] = (__bf16)(b1.z * QSCALE); fb[7] = (__bf16)(b1.w * QSCALE);
      qfA[kc] = fa; qfB[kc] = fb;
    }
  }

  float mA = 0.f, lA = 0.f, mB = 0.f, lB = 0.f;
  f32x4 accA[8], accB[8];
#pragma unroll
  for (int dt = 0; dt < 8; ++dt) {
    accA[dt] = (f32x4){0.f, 0.f, 0.f, 0.f};
    accB[dt] = (f32x4){0.f, 0.f, 0.f, 0.f};
  }

  // ---- staging invariants (128 lanes per group, 8 x 16B each per tile) ----
  const int gl = wv * 64 + lane;             // 0..127 within group
  const int slK = gl & 15;                   // K slot in row (const over j)
  const int Rb = gl >> 4;                    // K row base; rows Rb + 8j
  const int kcol = ((slK ^ (Rb & 7)) << 3);  // (Rb+8j)&7 == Rb&7
  const int svV = gl & 7;
  const int db = gl >> 3;                    // V dim base; dims db + 16j
  const int vcol = ((svV ^ (db & 7)) << 3);
  char* ldsK = (char*)&K_lds[g][0] + (size_t)gl * 16;
  char* ldsV = (char*)&V_lds[g][0] + (size_t)gl * 16;

  const int relA = wv * 32 + ln;
  const char* Kc = (const char*)&K_lds[g][0];
  const char* Vc = (const char*)&V_lds[g][0];

  for (int it = 0; it < n0; ++it) {
    const bool act = (it < myn);             // group-uniform
    const int kb = gbeg + it * KBLK;
    if (act) {
#pragma unroll
      for (int j = 0; j < 8; ++j) {
        const int R = Rb + 8 * j;
        const int c = R >> 4, r = R & 15;
        const int keyoff = ((c >> 1) << 5) + ((r >> 2) << 3) + ((c & 1) << 2) + (r & 3);
        gload16(KbH + (size_t)(kb + keyoff) * HN + kcol, ldsK + j * 2048);
      }
#pragma unroll
      for (int j = 0; j < 8; ++j)
        gload16(VbH + (size_t)(db + 16 * j) * T + kb + vcol, ldsV + j * 2048);
    }
    __syncthreads();  // drain DMA; tiles ready
    if (act) {
      if (kb >= r0)
        attn_iter<true>(Kc, Vc, qfA, qfB, ln, hi, relA - (kb - r0), mA, lA,
                        accA, mB, lB, accB);
      else
        attn_iter<false>(Kc, Vc, qfA, qfB, ln, hi, 0, mA, lA, accA, mB, lB, accB);
    }
    __syncthreads();  // LDS reuse guard before next stage
  }

  // ---- local split-K merge via LDS (group1 -> group0) ----
  float* accf = (float*)&K_lds[0][0];        // 64 x 128 f32 = 32 KB overlay
  if (g == 1) {
    if (hi == 0) {
      ml1[relA][0] = mA;      ml1[relA][1] = lA;
      ml1[relA + 16][0] = mB; ml1[relA + 16][1] = lB;
    }
#pragma unroll
    for (int dt = 0; dt < 8; ++dt) {
      *(f32x4*)&accf[relA * 128 + ((dt ^ (relA & 7)) << 4) + (hi << 2)] = accA[dt];
      *(f32x4*)&accf[(relA + 16) * 128 + ((dt ^ ((relA + 16) & 7)) << 4) + (hi << 2)] = accB[dt];
    }
  }
  __syncthreads();
  if (g == 0) {
#pragma unroll
    for (int set = 0; set < 2; ++set) {
      const int row = relA + set * 16;
      const float mg = set ? mB : mA;
      const float lg = set ? lB : lA;
      f32x4* acc = set ? accB : accA;
      const float m1 = ml1[row][0], l1v = ml1[row][1];
      float c0 = 1.f, c1 = 0.f, l = lg;
      if (l1v != 0.f) {
        const float m = fmaxf(mg, m1);
        c0 = exp2f(mg - m); c1 = exp2f(m1 - m);
        l = lg * c0 + l1v * c1;
      }
      const float inv = 1.0f / l;
      float* op = &O[(size_t)(r0 + row) * (NQH * HN) + h * HN];
#pragma unroll
      for (int dt = 0; dt < 8; ++dt) {
        const f32x4 a1 = *(const f32x4*)&accf[row * 128 + ((dt ^ (row & 7)) << 4) + (hi << 2)];
        const f32x4 res = (acc[dt] * c0 + a1 * c1) * inv;
        *(f32x4*)&op[dt * 16 + hi * 4] = res;
      }
    }
  }
}

extern "C" void kernel_launch(void* const* d_in, const int* in_sizes, int n_in,
                              void* d_out, int out_size, void* d_ws, size_t ws_size,
                              hipStream_t stream) {
  const float* Q = (const float*)d_in[0];
  const float* K = (const float*)d_in[1];
  const float* V = (const float*)d_in[2];
  const int* cu = (const int*)d_in[3];
  float* O = (float*)d_out;

  const int T = in_sizes[0] / (NQH * HN);  // 4096
  const int nseg = in_sizes[3] - 1;        // 4

  const size_t need = (size_t)2 * NKH * T * HN * sizeof(__bf16);  // 8 MB
  if (ws_size < need) return;

  __bf16* Kb = (__bf16*)d_ws;
  __bf16* Vb = (__bf16*)d_ws + (size_t)NKH * T * HN;

  const int nelem = T * NKH * HN;
  cvt_k<<<nelem / 8 / 256, 256, 0, stream>>>(K, Kb, T);
  cvt_v<<<dim3(T / 8, NKH), 128, 0, stream>>>(V, Vb, T);

  // 64 tiles x 16 heads, global heavy-first order (rank = blockIdx.x >> 4)
  attn_mfma9<<<1024, 256, 0, stream>>>(Q, Kb, Vb, cu, O, T, nseg);
}